// Round 8
// baseline (371.273 us; speedup 1.0000x reference)
//
#include <hip/hip_runtime.h>

static constexpr float NEG_SLOPE = 0.01f;
static constexpr float BN_EPS = 1e-5f;

using f16 = _Float16;
using f16x4 = __attribute__((ext_vector_type(4))) _Float16;
using f32x4 = __attribute__((ext_vector_type(4))) float;

// ---------------------------------------------------------------------------
__global__ __launch_bounds__(256) void sentinel_kernel(float* out, int m, float val) {
  int i = blockIdx.x * 256 + threadIdx.x;
  if (i < m) out[i] = val;
}

// zero deg (n ints) + stats (256 floats)
__global__ __launch_bounds__(256) void zero_kernel(int* __restrict__ deg,
                                                   float* __restrict__ stats, int n) {
  int stride = gridDim.x * blockDim.x;
  for (int i = blockIdx.x * blockDim.x + threadIdx.x; i < n; i += stride) deg[i] = 0;
  if (blockIdx.x == 0 && threadIdx.x < 256) stats[threadIdx.x] = 0.f;
}

// deg[v] += 1 per incoming edge; 4 independent edges per thread
__global__ __launch_bounds__(256) void deg_kernel(const int* __restrict__ col,
                                                  int* __restrict__ deg, int E) {
  int t = blockIdx.x * 256 + threadIdx.x;
  int S = gridDim.x * 256;
  int e0 = t, e1 = t + S, e2 = t + 2 * S, e3 = t + 3 * S;
  int v0 = (e0 < E) ? col[e0] : -1;
  int v1 = (e1 < E) ? col[e1] : -1;
  int v2 = (e2 < E) ? col[e2] : -1;
  int v3 = (e3 < E) ? col[e3] : -1;
  if (v0 >= 0) atomicAdd(&deg[v0], 1);
  if (v1 >= 0) atomicAdd(&deg[v1], 1);
  if (v2 >= 0) atomicAdd(&deg[v2], 1);
  if (v3 >= 0) atomicAdd(&deg[v3], 1);
}

// ---------------------------------------------------------------------------
// 3-phase exclusive scan of deg -> start (+cursor=end), plus dis = rsqrt(deg+1)
__global__ __launch_bounds__(256) void scan_partial(const int* __restrict__ deg,
                                                    int* __restrict__ partial, int n) {
  int i = blockIdx.x * 256 + threadIdx.x;
  int v = (i < n) ? deg[i] : 0;
  __shared__ int s[256];
  s[threadIdx.x] = v;
  __syncthreads();
  for (int off = 128; off; off >>= 1) {
    if (threadIdx.x < off) s[threadIdx.x] += s[threadIdx.x + off];
    __syncthreads();
  }
  if (threadIdx.x == 0) partial[blockIdx.x] = s[0];
}

__global__ __launch_bounds__(256) void scan_top(int* partial, int nb) {
  __shared__ int s[256];
  __shared__ int carry_s;
  if (threadIdx.x == 0) carry_s = 0;
  __syncthreads();
  for (int base = 0; base < nb; base += 256) {
    int i = base + threadIdx.x;
    int v = (i < nb) ? partial[i] : 0;
    s[threadIdx.x] = v;
    __syncthreads();
    for (int off = 1; off < 256; off <<= 1) {
      int t = (threadIdx.x >= off) ? s[threadIdx.x - off] : 0;
      __syncthreads();
      s[threadIdx.x] += t;
      __syncthreads();
    }
    int inc = s[threadIdx.x];
    int tot = s[255];
    int carry = carry_s;
    if (i < nb) partial[i] = carry + inc - v;
    __syncthreads();
    if (threadIdx.x == 0) carry_s = carry + tot;
    __syncthreads();
  }
}

__global__ __launch_bounds__(256) void scan_final(const int* __restrict__ deg,
                                                  const int* __restrict__ partial,
                                                  int* __restrict__ start,
                                                  int* __restrict__ cursor,
                                                  float* __restrict__ dis, int n, int E) {
  int i = blockIdx.x * 256 + threadIdx.x;
  int v = (i < n) ? deg[i] : 0;
  __shared__ int s[256];
  s[threadIdx.x] = v;
  __syncthreads();
  for (int off = 1; off < 256; off <<= 1) {
    int t = (threadIdx.x >= off) ? s[threadIdx.x - off] : 0;
    __syncthreads();
    s[threadIdx.x] += t;
    __syncthreads();
  }
  if (i < n) {
    int incl = partial[blockIdx.x] + s[threadIdx.x];
    start[i] = incl - v;
    cursor[i] = incl;  // end offset: atomicSub yields absolute csr slots
    dis[i] = rsqrtf((float)(v + 1));
  }
  if (i == 0) start[n] = E;
}

// csr[--cursor[v]] = row[e]; 4 independent edges per thread (4 atomic chains)
__global__ __launch_bounds__(256) void fill_kernel(
    const int* __restrict__ row, const int* __restrict__ colv,
    int* __restrict__ cursor, int* __restrict__ csr, int E) {
  int t = blockIdx.x * 256 + threadIdx.x;
  int S = gridDim.x * 256;
  int e0 = t, e1 = t + S, e2 = t + 2 * S, e3 = t + 3 * S;
  bool b0 = e0 < E, b1 = e1 < E, b2 = e2 < E, b3 = e3 < E;
  int v0 = 0, v1 = 0, v2 = 0, v3 = 0, r0 = 0, r1 = 0, r2 = 0, r3 = 0;
  if (b0) { v0 = colv[e0]; r0 = row[e0]; }
  if (b1) { v1 = colv[e1]; r1 = row[e1]; }
  if (b2) { v2 = colv[e2]; r2 = row[e2]; }
  if (b3) { v3 = colv[e3]; r3 = row[e3]; }
  int o0 = 0, o1 = 0, o2 = 0, o3 = 0;
  if (b0) o0 = atomicSub(&cursor[v0], 1) - 1;
  if (b1) o1 = atomicSub(&cursor[v1], 1) - 1;
  if (b2) o2 = atomicSub(&cursor[v2], 1) - 1;
  if (b3) o3 = atomicSub(&cursor[v3], 1) - 1;
  if (b0) csr[o0] = r0;
  if (b1) csr[o1] = r1;
  if (b2) csr[o2] = r2;
  if (b3) csr[o3] = r3;
}

// ---------------------------------------------------------------------------
// MFMA GEMM: g[r,c] = ((A[r,:](*sc) @ W[:,c]) + cadd[c]) * dis[r], fp16 out.
template <int KD, bool FOLD, bool A_HALF>
__global__ __launch_bounds__(256) void mfma_gemm(
    const void* __restrict__ Aptr, const float* __restrict__ W,
    const float* __restrict__ sc, const float* __restrict__ cadd,
    const float* __restrict__ dis, f16* __restrict__ g, int n) {
  constexpr int NKT = KD / 16;
  const int lane = threadIdx.x & 63;
  const int wq = threadIdx.x >> 6;
  const int lr = lane & 15;
  const int kb = (lane >> 4) * 4;

  f16x4 bfrag[NKT][4];
#pragma unroll
  for (int kt = 0; kt < NKT; ++kt)
#pragma unroll
    for (int ct = 0; ct < 4; ++ct) {
#pragma unroll
      for (int j = 0; j < 4; ++j) {
        int k = kt * 16 + kb + j;
        float w = W[k * 64 + ct * 16 + lr];
        if (FOLD) w *= sc[k];
        bfrag[kt][ct][j] = (f16)w;
      }
    }
  float cl[4];
#pragma unroll
  for (int ct = 0; ct < 4; ++ct) cl[ct] = FOLD ? cadd[ct * 16 + lr] : 0.f;

  const int ntiles = (n + 15) >> 4;
  for (int t = blockIdx.x * 4 + wq; t < ntiles; t += gridDim.x * 4) {
    const int r0 = t << 4;
    int arow = r0 + lr;
    if (arow >= n) arow = n - 1;
    f16x4 afrag[NKT];
    if (A_HALF) {
      const f16* Ah = (const f16*)Aptr;
#pragma unroll
      for (int kt = 0; kt < NKT; ++kt)
        afrag[kt] = *reinterpret_cast<const f16x4*>(Ah + (size_t)arow * KD + kt * 16 + kb);
    } else {
      const float* Af = (const float*)Aptr;
#pragma unroll
      for (int kt = 0; kt < NKT; ++kt) {
        f32x4 xa = *reinterpret_cast<const f32x4*>(Af + (size_t)arow * KD + kt * 16 + kb);
        f16x4 a;
        a[0] = (f16)xa[0]; a[1] = (f16)xa[1]; a[2] = (f16)xa[2]; a[3] = (f16)xa[3];
        afrag[kt] = a;
      }
    }
    f32x4 acc[4];
#pragma unroll
    for (int ct = 0; ct < 4; ++ct) acc[ct] = (f32x4){0.f, 0.f, 0.f, 0.f};
#pragma unroll
    for (int kt = 0; kt < NKT; ++kt)
#pragma unroll
      for (int ct = 0; ct < 4; ++ct)
        acc[ct] = __builtin_amdgcn_mfma_f32_16x16x16f16(afrag[kt], bfrag[kt][ct], acc[ct], 0, 0, 0);
    if (r0 + 16 <= n) {
#pragma unroll
      for (int v = 0; v < 4; ++v) {
        int grow = r0 + (lane >> 4) * 4 + v;
        float dv = dis[grow];
#pragma unroll
        for (int ct = 0; ct < 4; ++ct)
          g[(size_t)grow * 64 + ct * 16 + lr] = (f16)((acc[ct][v] + cl[ct]) * dv);
      }
    } else {
      for (int v = 0; v < 4; ++v) {
        int grow = r0 + (lane >> 4) * 4 + v;
        if (grow < n) {
          float dv = dis[grow];
          for (int ct = 0; ct < 4; ++ct)
            g[(size_t)grow * 64 + ct * 16 + lr] = (f16)((acc[ct][v] + cl[ct]) * dv);
        }
      }
    }
  }
}

// ---------------------------------------------------------------------------
// t[v] = leaky(dis[v]*(g[v] + sum_{u in CSR[v]} g[u]) + bias); stats sum/sumsq.
// TWO nodes per wave iteration -> ~32 gathers in flight per wave.
template <typename OutT>
__global__ __launch_bounds__(256) void gather_post(
    const f16* __restrict__ g, const int* __restrict__ csr,
    const int* __restrict__ start, const float* __restrict__ dis,
    const float* __restrict__ bias, OutT* __restrict__ t_out,
    float* __restrict__ stats, int n) {
  const int lane = threadIdx.x & 63;
  const float bd = bias[lane];
  const f16* gl = g + lane;
  const int wid = (blockIdx.x * 256 + threadIdx.x) >> 6;
  const int nw = (gridDim.x * 256) >> 6;
  float lsum = 0.f, lsq = 0.f;
  for (int v0 = wid * 2; v0 < n; v0 += nw * 2) {
    const int v1 = v0 + 1;
    const bool hasB = (v1 < n);
    int2 sv = *reinterpret_cast<const int2*>(start + v0);
    const int s0a = sv.x, s1a = sv.y;
    const int s0b = s1a;
    const int s1b = hasB ? start[v0 + 2] : s1a;
    float suma = (float)gl[v0 * 64];
    float sumb = hasB ? (float)gl[v1 * 64] : 0.f;
    int ea = s0a, eb = s0b;
    int nbat_a = (s1a - s0a + 15) >> 4;
    int nbat_b = (s1b - s0b + 15) >> 4;
    int nbatch = nbat_a > nbat_b ? nbat_a : nbat_b;
    for (int b = 0; b < nbatch; ++b) {
      int ua[16], ub[16];
#pragma unroll
      for (int i = 0; i < 16; ++i) ua[i] = (ea + i < s1a) ? csr[ea + i] : v0;
#pragma unroll
      for (int i = 0; i < 16; ++i) ub[i] = (eb + i < s1b) ? csr[eb + i] : v0;
      float fa[16], fb[16];
#pragma unroll
      for (int i = 0; i < 16; ++i) fa[i] = (float)gl[ua[i] * 64];
#pragma unroll
      for (int i = 0; i < 16; ++i) fb[i] = (float)gl[ub[i] * 64];
      float pa = 0.f, pb = 0.f;
#pragma unroll
      for (int i = 0; i < 16; ++i) pa += (ea + i < s1a) ? fa[i] : 0.f;
#pragma unroll
      for (int i = 0; i < 16; ++i) pb += (eb + i < s1b) ? fb[i] : 0.f;
      suma += pa;
      sumb += pb;
      ea += 16;
      eb += 16;
    }
    float ta = dis[v0] * suma + bd;
    ta = (ta > 0.f) ? ta : NEG_SLOPE * ta;
    t_out[(size_t)v0 * 64 + lane] = (OutT)ta;
    lsum += ta;
    lsq += ta * ta;
    if (hasB) {
      float tb = dis[v1] * sumb + bd;
      tb = (tb > 0.f) ? tb : NEG_SLOPE * tb;
      t_out[(size_t)v1 * 64 + lane] = (OutT)tb;
      lsum += tb;
      lsq += tb * tb;
    }
  }
  __shared__ float red[256];
  red[threadIdx.x] = lsum;
  __syncthreads();
  if (threadIdx.x < 64)
    atomicAdd(&stats[lane],
              red[threadIdx.x] + red[threadIdx.x + 64] + red[threadIdx.x + 128] + red[threadIdx.x + 192]);
  __syncthreads();
  red[threadIdx.x] = lsq;
  __syncthreads();
  if (threadIdx.x < 64)
    atomicAdd(&stats[64 + lane],
              red[threadIdx.x] + red[threadIdx.x + 64] + red[threadIdx.x + 128] + red[threadIdx.x + 192]);
}

// ---------------------------------------------------------------------------
// BN fold params: sc[d]=gamma*rstd, sh[d]=beta-mu*sc; if withC also
// c[j] = sum_k sh[k]*W[k,j].
__global__ __launch_bounds__(64) void bnparam_kernel(
    const float* __restrict__ stats, const float* __restrict__ gamma,
    const float* __restrict__ beta, const float* __restrict__ W,
    float* __restrict__ outp, int n, int withC) {
  int d = threadIdx.x;
  __shared__ float ssh[64];
  float inv_n = 1.0f / (float)n;
  float mu = stats[d] * inv_n;
  float var = stats[64 + d] * inv_n - mu * mu;
  float r = rsqrtf(var + BN_EPS);
  float s = gamma[d] * r;
  float sh = beta[d] - mu * s;
  outp[d] = s;
  outp[64 + d] = sh;
  ssh[d] = sh;
  __syncthreads();
  if (withC) {
    float c = 0.f;
    for (int k = 0; k < 64; ++k) c = fmaf(ssh[k], W[k * 64 + d], c);
    outp[128 + d] = c;
  }
}

// fused: h_sel = t[idx]*sc1+sh1; out2 = sigmoid(h_sel@Wm+bm)
__global__ __launch_bounds__(256) void selmlp_kernel(
    const float* __restrict__ t, const int* __restrict__ idx,
    const float* __restrict__ bnp, const float* __restrict__ Wm,
    const float* __restrict__ bm, float* __restrict__ out,
    float* __restrict__ out2, int K) {
  const int lane = threadIdx.x & 63;
  int w = (blockIdx.x * 256 + threadIdx.x) >> 6;
  if (w >= K) return;
  int v = idx[w];
  float hv = fmaf(t[(size_t)v * 64 + lane], bnp[lane], bnp[64 + lane]);
  out[(size_t)w * 64 + lane] = hv;
#pragma unroll
  for (int j = 0; j < 5; ++j) {
    float p = hv * Wm[lane * 5 + j];
#pragma unroll
    for (int off = 32; off; off >>= 1) p += __shfl_xor(p, off);
    if (lane == 0) out2[(size_t)w * 5 + j] = 1.f / (1.f + expf(-(p + bm[j])));
  }
}

// ---------------------------------------------------------------------------
extern "C" void kernel_launch(void* const* d_in, const int* in_sizes, int n_in,
                              void* d_out, int out_size, void* d_ws, size_t ws_size,
                              hipStream_t stream) {
  const float* x      = (const float*)d_in[0];
  const int*   eidx   = (const int*)d_in[1];
  const int*   idx    = (const int*)d_in[2];
  const float* W0     = (const float*)d_in[3];
  const float* b0     = (const float*)d_in[4];
  const float* gamma0 = (const float*)d_in[5];
  const float* beta0  = (const float*)d_in[6];
  const float* W1     = (const float*)d_in[7];
  const float* b1     = (const float*)d_in[8];
  const float* gamma1 = (const float*)d_in[9];
  const float* beta1  = (const float*)d_in[10];
  const float* Wm     = (const float*)d_in[11];
  const float* bm     = (const float*)d_in[12];

  const int n = in_sizes[0] / 128;
  const int E = in_sizes[1] / 2;
  const int K = in_sizes[2];
  const int* erow = eidx;      // sources  (edge_index[0])
  const int* ecol = eidx + E;  // targets  (edge_index[1])
  const int nb = (n + 255) / 256;

  size_t needed = (size_t)n * 64 * 4          // tf
                + 256 * 4 + 320 * 4           // stats + bn params
                + (size_t)n * 4               // dis
                + (size_t)n * 4               // deg
                + (size_t)(n + 1) * 4         // start
                + (size_t)n * 4               // cursor
                + (size_t)(E + 16) * 4        // csr
                + (size_t)(nb + 1) * 4        // partial
                + (size_t)n * 64 * 2          // gh
                + (size_t)n * 64 * 2;         // t0h
  if (ws_size < needed) {
    sentinel_kernel<<<dim3((out_size + 255) / 256), dim3(256), 0, stream>>>(
        (float*)d_out, out_size, 1e6f);
    return;
  }
  float* tf    = (float*)d_ws;                 // n*64 f32
  float* stats = tf + (size_t)n * 64;          // 256
  float* bnp   = stats + 256;                  // 320
  float* dis   = bnp + 320;                    // n
  int*   deg   = (int*)(dis + n);              // n
  int*   start = deg + n;                      // n+1
  int*   cursor = start + (n + 1);             // n
  int*   csr   = cursor + n;                   // E+16
  int*   partial = csr + (E + 16);             // nb+1
  f16*   gh    = (f16*)(partial + nb + 1);     // n*64 fp16
  f16*   t0h   = gh + (size_t)n * 64;          // n*64 fp16

  dim3 blk(256);
  const int eb4 = (E + 1023) / 1024;
  // ---- graph preprocessing ----
  zero_kernel<<<dim3(nb), blk, 0, stream>>>(deg, stats, n);
  deg_kernel<<<dim3(eb4), blk, 0, stream>>>(ecol, deg, E);
  scan_partial<<<dim3(nb), blk, 0, stream>>>(deg, partial, n);
  scan_top<<<dim3(1), blk, 0, stream>>>(partial, nb);
  scan_final<<<dim3(nb), blk, 0, stream>>>(deg, partial, start, cursor, dis, n, E);
  fill_kernel<<<dim3(eb4), blk, 0, stream>>>(erow, ecol, cursor, csr, E);

  // ---- layer 0 ----
  mfma_gemm<128, false, false><<<dim3(640), blk, 0, stream>>>(
      x, W0, nullptr, nullptr, dis, gh, n);
  gather_post<f16><<<dim3(2048), blk, 0, stream>>>(gh, csr, start, dis, b0, t0h, stats, n);
  bnparam_kernel<<<dim3(1), dim3(64), 0, stream>>>(stats, gamma0, beta0, W1, bnp, n, 1);
  // ---- layer 1 (BN0 folded into GEMM) ----
  mfma_gemm<64, true, true><<<dim3(640), blk, 0, stream>>>(
      t0h, W1, bnp, bnp + 128, dis, gh, n);
  gather_post<float><<<dim3(2048), blk, 0, stream>>>(gh, csr, start, dis, b1, tf, stats + 128, n);
  bnparam_kernel<<<dim3(1), dim3(64), 0, stream>>>(
      stats + 128, gamma1, beta1, nullptr, bnp + 192, n, 0);
  // ---- select + MLP (BN1 folded in) ----
  selmlp_kernel<<<dim3((K + 3) / 4), blk, 0, stream>>>(
      tf, idx, bnp + 192, Wm, bm, (float*)d_out, (float*)d_out + (size_t)K * 64, K);
}